// Round 3
// baseline (207.690 us; speedup 1.0000x reference)
//
#include <hip/hip_runtime.h>
#include <hip/hip_bf16.h>

#define BATCH 16
#define C 768
#define T 8
#define R 64
#define HW 4096
#define NPS (HW*C)   // 3145728 elements per sample
#define GN_EPS 1e-5f

typedef short bf16x8 __attribute__((ext_vector_type(8)));
typedef float f32x4 __attribute__((ext_vector_type(4)));

static __device__ __forceinline__ unsigned short f2bf(float f) {
    __hip_bfloat16 h = __float2bfloat16(f);
    return *reinterpret_cast<unsigned short*>(&h);
}

// ---------------- kernel 1: zero stats + convert weights to bf16 ----------------
__global__ __launch_bounds__(256) void prep_kernel(const float* __restrict__ Wdn,
                                                   const float* __restrict__ Wup,
                                                   float* __restrict__ stats,
                                                   unsigned short* __restrict__ wd_bf,
                                                   unsigned short* __restrict__ wu_bf) {
    int idx = blockIdx.x * 256 + threadIdx.x;   // 0..196607, each handles one float4
    if (blockIdx.x == 0 && threadIdx.x < 32) stats[threadIdx.x] = 0.f;
    const int NF4 = T * R * C / 4;              // 98304 float4 per weight tensor
    const float4* src;
    unsigned short* dst;
    int j;
    if (idx < NF4) { src = (const float4*)Wdn; dst = wd_bf; j = idx; }
    else           { src = (const float4*)Wup; dst = wu_bf; j = idx - NF4; }
    float4 v = src[j];
    ushort4 o;
    o.x = f2bf(v.x); o.y = f2bf(v.y); o.z = f2bf(v.z); o.w = f2bf(v.w);
    *reinterpret_cast<ushort4*>(dst + j * 4) = o;
}

// ---------------- kernel 2: per-sample sum / sumsq ----------------
__global__ __launch_bounds__(256) void stats_kernel(const float* __restrict__ x,
                                                    float* __restrict__ stats) {
    int b = blockIdx.y;
    const float4* xp = (const float4*)(x + (size_t)b * NPS);
    float s = 0.f, q = 0.f;
    int base = blockIdx.x * 256 + threadIdx.x;  // grid.x = 48 -> 12288 threads
    #pragma unroll 4
    for (int i = 0; i < 64; i++) {
        float4 v = xp[(size_t)i * 12288 + base];
        s += v.x + v.y + v.z + v.w;
        q += v.x*v.x + v.y*v.y + v.z*v.z + v.w*v.w;
    }
    for (int off = 32; off > 0; off >>= 1) {
        s += __shfl_down(s, off);
        q += __shfl_down(q, off);
    }
    __shared__ float ps[4], pq[4];
    int wave = threadIdx.x >> 6, lane = threadIdx.x & 63;
    if (lane == 0) { ps[wave] = s; pq[wave] = q; }
    __syncthreads();
    if (threadIdx.x == 0) {
        float S = 0.f, Q = 0.f;
        #pragma unroll
        for (int wv = 0; wv < 4; wv++) { S += ps[wv]; Q += pq[wv]; }
        atomicAdd(&stats[2*b],   S);
        atomicAdd(&stats[2*b+1], Q);
    }
}

// ---------------- kernel 3: fused normalize + GEMM1 + gelu + GEMM2 + residual ----------------
// grid (64 tiles, 16 samples), 256 threads = 4 waves, each wave owns 16 x-rows.
// Operand-swapped MFMAs: A = weights (contiguous 16B frags), B = activations^T.
// D layout (row=channel, col=x-row) => each thread holds 4 consecutive channels
// => fully vectorized float4 residual epilogue. h lives in swizzled LDS,
// wave-private rows => no barrier between GEMM1 and GEMM2.
__global__ __launch_bounds__(256, 4) void fused_kernel(
        const float* __restrict__ x, const int* __restrict__ task_ids,
        const float* __restrict__ gamma, const float* __restrict__ beta,
        const float* __restrict__ scales, const float* __restrict__ stats,
        const unsigned short* __restrict__ wd_bf, const unsigned short* __restrict__ wu_bf,
        float* __restrict__ out) {
    __shared__ float coefA[C];                // rstd*gamma
    __shared__ float coefB[C];                // beta - mean*rstd*gamma
    __shared__ unsigned short hs[64 * 64];    // 8 KiB gelu(h), row stride 128B, XOR-swizzled

    int tile = blockIdx.x, b = blockIdx.y;
    int tid = threadIdx.x;
    int t = task_ids[b];
    float sc = scales[t];
    float s1 = stats[2*b], s2 = stats[2*b+1];
    float mean = s1 * (1.f / NPS);
    float var  = s2 * (1.f / NPS) - mean * mean;
    float rstd = rsqrtf(var + GN_EPS);

    // ---- stage normalization coefficients into LDS (one-time) ----
    if (tid < 192) {
        float4 g  = ((const float4*)gamma)[tid];
        float4 be = ((const float4*)beta)[tid];
        float4 ca, cb;
        ca.x = rstd * g.x; cb.x = be.x - mean * ca.x;
        ca.y = rstd * g.y; cb.y = be.y - mean * ca.y;
        ca.z = rstd * g.z; cb.z = be.z - mean * ca.z;
        ca.w = rstd * g.w; cb.w = be.w - mean * ca.w;
        ((float4*)coefA)[tid] = ca;
        ((float4*)coefB)[tid] = cb;
    }
    __syncthreads();

    size_t xbase = (size_t)b * NPS + (size_t)tile * 64 * C;
    int wave = tid >> 6, lane = tid & 63;
    int m0 = wave * 16;
    int lr = lane & 15, lg = lane >> 4;
    int row = m0 + lr;                        // this lane's x-row (B-frag column)

    // ---- GEMM1: h^T[R x 64rows] = Wd[R x C] * x_norm^T, A=Wd, B=x_norm^T ----
    const unsigned short* wd = wd_bf + t * (R * C);
    const float* xb = x + xbase + (size_t)row * C + lg * 8;  // lane's k-strip base
    f32x4 acc1[4] = {};
    float4 pA0 = *reinterpret_cast<const float4*>(xb);
    float4 pA1 = *reinterpret_cast<const float4*>(xb + 4);
    float4 pB0 = *reinterpret_cast<const float4*>(xb + 32);
    float4 pB1 = *reinterpret_cast<const float4*>(xb + 36);
    for (int k = 0; k < 24; k += 2) {
        // --- sub-iter A (uses pA, prefetches k+2) ---
        {
            int col = k * 32 + lg * 8;
            float4 ca0 = *reinterpret_cast<const float4*>(coefA + col);
            float4 ca1 = *reinterpret_cast<const float4*>(coefA + col + 4);
            float4 cb0 = *reinterpret_cast<const float4*>(coefB + col);
            float4 cb1 = *reinterpret_cast<const float4*>(coefB + col + 4);
            bf16x8 bf;
            bf[0] = (short)f2bf(pA0.x * ca0.x + cb0.x);
            bf[1] = (short)f2bf(pA0.y * ca0.y + cb0.y);
            bf[2] = (short)f2bf(pA0.z * ca0.z + cb0.z);
            bf[3] = (short)f2bf(pA0.w * ca0.w + cb0.w);
            bf[4] = (short)f2bf(pA1.x * ca1.x + cb1.x);
            bf[5] = (short)f2bf(pA1.y * ca1.y + cb1.y);
            bf[6] = (short)f2bf(pA1.z * ca1.z + cb1.z);
            bf[7] = (short)f2bf(pA1.w * ca1.w + cb1.w);
            if (k + 2 < 24) {
                pA0 = *reinterpret_cast<const float4*>(xb + (k + 2) * 32);
                pA1 = *reinterpret_cast<const float4*>(xb + (k + 2) * 32 + 4);
            }
            #pragma unroll
            for (int rg = 0; rg < 4; rg++) {
                bf16x8 af = *reinterpret_cast<const bf16x8*>(wd + (rg * 16 + lr) * C + k * 32 + lg * 8);
                acc1[rg] = __builtin_amdgcn_mfma_f32_16x16x32_bf16(af, bf, acc1[rg], 0, 0, 0);
            }
        }
        // --- sub-iter B (uses pB, prefetches k+3) ---
        {
            int k1 = k + 1;
            int col = k1 * 32 + lg * 8;
            float4 ca0 = *reinterpret_cast<const float4*>(coefA + col);
            float4 ca1 = *reinterpret_cast<const float4*>(coefA + col + 4);
            float4 cb0 = *reinterpret_cast<const float4*>(coefB + col);
            float4 cb1 = *reinterpret_cast<const float4*>(coefB + col + 4);
            bf16x8 bf;
            bf[0] = (short)f2bf(pB0.x * ca0.x + cb0.x);
            bf[1] = (short)f2bf(pB0.y * ca0.y + cb0.y);
            bf[2] = (short)f2bf(pB0.z * ca0.z + cb0.z);
            bf[3] = (short)f2bf(pB0.w * ca0.w + cb0.w);
            bf[4] = (short)f2bf(pB1.x * ca1.x + cb1.x);
            bf[5] = (short)f2bf(pB1.y * ca1.y + cb1.y);
            bf[6] = (short)f2bf(pB1.z * ca1.z + cb1.z);
            bf[7] = (short)f2bf(pB1.w * ca1.w + cb1.w);
            if (k1 + 2 < 24) {
                pB0 = *reinterpret_cast<const float4*>(xb + (k1 + 2) * 32);
                pB1 = *reinterpret_cast<const float4*>(xb + (k1 + 2) * 32 + 4);
            }
            #pragma unroll
            for (int rg = 0; rg < 4; rg++) {
                bf16x8 af = *reinterpret_cast<const bf16x8*>(wd + (rg * 16 + lr) * C + k1 * 32 + lg * 8);
                acc1[rg] = __builtin_amdgcn_mfma_f32_16x16x32_bf16(af, bf, acc1[rg], 0, 0, 0);
            }
        }
    }

    // ---- exact gelu; h -> swizzled LDS. D: row=R-chan (lg*4+j), col=x-row (lr) ----
    char* hsb = (char*)hs;
    #pragma unroll
    for (int rg = 0; rg < 4; rg++) {
        ushort4 o;
        float v0 = acc1[rg][0], v1 = acc1[rg][1], v2 = acc1[rg][2], v3 = acc1[rg][3];
        o.x = f2bf(0.5f * v0 * (1.f + erff(v0 * 0.70710678118f)));
        o.y = f2bf(0.5f * v1 * (1.f + erff(v1 * 0.70710678118f)));
        o.z = f2bf(0.5f * v2 * (1.f + erff(v2 * 0.70710678118f)));
        o.w = f2bf(0.5f * v3 * (1.f + erff(v3 * 0.70710678118f)));
        // h[row=x-row][chan]: x-row = m0+lr, chan = rg*16 + lg*4 .. +3  (8B write)
        int byte = (m0 + lr) * 128 + rg * 32 + lg * 8;
        byte ^= ((lr & 7) << 4);
        *reinterpret_cast<ushort4*>(hsb + byte) = o;
    }
    // hs rows are wave-private (each wave reads only its own 16 rows) -> no barrier.

    // ---- GEMM2: delta^T[C x 64rows] = Wu[C x R] * h^T, fused residual ----
    bf16x8 b2[2];
    #pragma unroll
    for (int k2 = 0; k2 < 2; k2++) {
        int byte = row * 128 + k2 * 64 + lg * 16;
        byte ^= ((lr & 7) << 4);
        b2[k2] = *reinterpret_cast<const bf16x8*>(hsb + byte);
    }
    const unsigned short* wu = wu_bf + t * (C * R);
    const float* xr = x + xbase;
    float* outp = out + xbase;
    for (int cn = 0; cn < 6; cn++) {
        f32x4 acc2[8] = {};
        #pragma unroll
        for (int cg = 0; cg < 8; cg++) {
            int crow = cn * 128 + cg * 16 + lr;
            bf16x8 a0 = *reinterpret_cast<const bf16x8*>(wu + crow * R + lg * 8);
            bf16x8 a1 = *reinterpret_cast<const bf16x8*>(wu + crow * R + 32 + lg * 8);
            acc2[cg] = __builtin_amdgcn_mfma_f32_16x16x32_bf16(a0, b2[0], acc2[cg], 0, 0, 0);
            acc2[cg] = __builtin_amdgcn_mfma_f32_16x16x32_bf16(a1, b2[1], acc2[cg], 0, 0, 0);
        }
        // epilogue: thread holds channels c0..c0+3 at x-row `row` -> float4 I/O
        #pragma unroll
        for (int cg = 0; cg < 8; cg++) {
            int c0 = cn * 128 + cg * 16 + lg * 4;
            size_t off = (size_t)row * C + c0;
            float4 xv = *reinterpret_cast<const float4*>(xr + off);
            float4 ov;
            ov.x = xv.x + sc * acc2[cg][0];
            ov.y = xv.y + sc * acc2[cg][1];
            ov.z = xv.z + sc * acc2[cg][2];
            ov.w = xv.w + sc * acc2[cg][3];
            *reinterpret_cast<float4*>(outp + off) = ov;
        }
    }
}

extern "C" void kernel_launch(void* const* d_in, const int* in_sizes, int n_in,
                              void* d_out, int out_size, void* d_ws, size_t ws_size,
                              hipStream_t stream) {
    const float* x        = (const float*)d_in[0];
    const int*   task_ids = (const int*)d_in[1];
    const float* gamma    = (const float*)d_in[2];
    const float* beta     = (const float*)d_in[3];
    const float* W_down   = (const float*)d_in[4];
    const float* W_up     = (const float*)d_in[5];
    const float* scales   = (const float*)d_in[6];
    float* out = (float*)d_out;

    // workspace layout: [0,128): stats (16 x {sum,sumsq}); then bf16 weights
    float* stats = (float*)d_ws;
    unsigned short* wd_bf = (unsigned short*)((char*)d_ws + 128);
    unsigned short* wu_bf = wd_bf + T * R * C;

    // 1) zero stats + convert weights (2*98304 float4 jobs / 256 = 768 blocks)
    prep_kernel<<<768, 256, 0, stream>>>(W_down, W_up, stats, wd_bf, wu_bf);
    // 2) per-sample stats
    stats_kernel<<<dim3(48, BATCH), 256, 0, stream>>>(x, stats);
    // 3) fused adapter
    fused_kernel<<<dim3(64, BATCH), 256, 0, stream>>>(
        x, task_ids, gamma, beta, scales, stats, wd_bf, wu_bf, out);
}